// Round 17
// baseline (166.511 us; speedup 1.0000x reference)
//
#include <hip/hip_runtime.h>
#include <math.h>

#define B_   32
#define C_   64
#define F_   128
#define TP_  32
#define G_   (B_*TP_)      // 1024 graphs
#define NHID 256
#define NOUT 128
#define E_   512
#define K1_  52            // ceil(0.8*64)
#define K2_  42            // ceil(0.8*52)

typedef __attribute__((ext_vector_type(8))) short short8_t;   // 8 bf16 (4 VGPR)
typedef __attribute__((ext_vector_type(4))) float f32x4_t;

__device__ __forceinline__ void split_bf16(float v, unsigned short &h, unsigned short &l) {
  unsigned u = __float_as_uint(v);
  unsigned hb = (u + 0x7FFFu + ((u >> 16) & 1u)) & 0xFFFF0000u;  // RNE bf16 of v
  float hf = __uint_as_float(hb);
  float r = v - hf;                                              // exact in f32
  unsigned ur = __float_as_uint(r);
  unsigned lb = (ur + 0x7FFFu + ((ur >> 16) & 1u)) >> 16;        // RNE bf16 of r
  h = (unsigned short)(hb >> 16);
  l = (unsigned short)lb;
}

// RNE 3-limb split (used for weights, one-time prep)
__device__ __forceinline__ void split3_bf16(float v, unsigned short &h,
                                            unsigned short &m, unsigned short &l) {
  unsigned u = __float_as_uint(v);
  unsigned hb = (u + 0x7FFFu + ((u >> 16) & 1u)) & 0xFFFF0000u;
  float hf = __uint_as_float(hb);
  float r1 = v - hf;                                             // exact
  unsigned u1 = __float_as_uint(r1);
  unsigned mb = (u1 + 0x7FFFu + ((u1 >> 16) & 1u)) & 0xFFFF0000u;
  float mf = __uint_as_float(mb);
  float r2 = r1 - mf;                                            // exact
  unsigned u2 = __float_as_uint(r2);
  unsigned lb = (u2 + 0x7FFFu + ((u2 >> 16) & 1u)) >> 16;
  h = (unsigned short)(hb >> 16);
  m = (unsigned short)(mb >> 16);
  l = (unsigned short)lb;
}

// cheap 3-limb split: trunc hi/mid (exact remainders), RNE last limb. err <= 2^-22|v|
__device__ __forceinline__ void split3t_bf16(float v, unsigned short &h,
                                             unsigned short &m, unsigned short &l) {
  unsigned u = __float_as_uint(v);
  float hf = __uint_as_float(u & 0xFFFF0000u);
  float r1 = v - hf;                                             // exact
  unsigned u1 = __float_as_uint(r1);
  float mf = __uint_as_float(u1 & 0xFFFF0000u);
  float r2 = r1 - mf;                                            // exact
  unsigned u2 = __float_as_uint(r2);
  unsigned lb = (u2 + 0x7FFFu + ((u2 >> 16) & 1u)) >> 16;        // RNE
  h = (unsigned short)(u >> 16);
  m = (unsigned short)(u1 >> 16);
  l = (unsigned short)lb;
}

// ---- prep_all: block 0 -> build A1/As1; blocks 1..64 -> w1prep; 65..128 -> w2prep ---
__global__ __launch_bounds__(256) void prep_all(const int* __restrict__ ei,
                                                const float* __restrict__ ew,
                                                const float* __restrict__ W1,
                                                const float* __restrict__ W2,
                                                float* __restrict__ A1,
                                                float* __restrict__ As1,
                                                unsigned short* __restrict__ W1hi,
                                                unsigned short* __restrict__ W1lo,
                                                unsigned short* __restrict__ W2hi,
                                                unsigned short* __restrict__ W2mid,
                                                unsigned short* __restrict__ W2lo) {
  int t = threadIdx.x;
  int blk = blockIdx.x;
  if (blk == 0) {
    __shared__ float A1s[C_*C_], As1s[C_*C_];
    __shared__ float dg[C_], dgs[C_], dis[C_], diss[C_];
    for (int i = t; i < C_*C_; i += 256) { A1s[i] = 0.f; As1s[i] = 0.f; }
    if (t < C_) { dg[t] = 1.f; dgs[t] = 1.f; }   // self-loop weight 1
    int r0[2], c0[2]; float w0[2];
#pragma unroll
    for (int p = 0; p < 2; ++p) {
      int e = t + p*256;
      r0[p] = ei[e]; c0[p] = ei[E_ + e]; w0[p] = ew[e];
    }
    __syncthreads();
#pragma unroll
    for (int p = 0; p < 2; ++p) {
      atomicAdd(&dg[c0[p]], w0[p]);
      atomicAdd(&dgs[c0[p]], 1.f);
    }
    __syncthreads();
    if (t < C_) { dis[t] = rsqrtf(dg[t]); diss[t] = rsqrtf(dgs[t]); }
    __syncthreads();
#pragma unroll
    for (int p = 0; p < 2; ++p) {
      int r = r0[p], c = c0[p];
      atomicAdd(&A1s[c*C_ + r],  dis[r] * w0[p] * dis[c]);
      atomicAdd(&As1s[c*C_ + r], diss[r] * diss[c]);
    }
    if (t < C_) {
      atomicAdd(&A1s[t*C_ + t],  dis[t] * dis[t]);
      atomicAdd(&As1s[t*C_ + t], diss[t] * diss[t]);
    }
    __syncthreads();
    for (int i = t; i < C_*C_; i += 256) { A1[i] = A1s[i]; As1[i] = As1s[i]; }
  } else if (blk <= 64) {
    int tid = (blk - 1)*256 + t;              // 16384 threads, 2 k's each
    int col = tid >> 6, k2 = tid & 63;
    float v0 = W1[(size_t)(2*k2)*NHID + col];
    float v1 = W1[(size_t)(2*k2+1)*NHID + col];
    unsigned short h0,l0,h1,l1;
    split_bf16(v0, h0, l0);
    split_bf16(v1, h1, l1);
    *(unsigned*)&W1hi[(size_t)col*128 + 2*k2] = (unsigned)h0 | ((unsigned)h1 << 16);
    *(unsigned*)&W1lo[(size_t)col*128 + 2*k2] = (unsigned)l0 | ((unsigned)l1 << 16);
  } else {
    int tid = (blk - 65)*256 + t;             // 16384 threads, 2 k's each
    int col = tid >> 7, k2 = tid & 127;
    float v0 = W2[(size_t)(2*k2)*NOUT + col];
    float v1 = W2[(size_t)(2*k2+1)*NOUT + col];
    unsigned short h0,m0,l0,h1,m1,l1;
    split3_bf16(v0, h0, m0, l0);
    split3_bf16(v1, h1, m1, l1);
    *(unsigned*)&W2hi [(size_t)col*256 + 2*k2] = (unsigned)h0 | ((unsigned)h1 << 16);
    *(unsigned*)&W2mid[(size_t)col*256 + 2*k2] = (unsigned)m0 | ((unsigned)m1 << 16);
    *(unsigned*)&W2lo [(size_t)col*256 + 2*k2] = (unsigned)l0 | ((unsigned)l1 << 16);
  }
}

// ---- preagg: xa2[b,c,f,tp] = sum_j A1[c,j] * h[b,j,f,tp]  (per-b, (f,tp) cols) ------
__global__ __launch_bounds__(256) void preagg_b(const float* __restrict__ h,
                                                const float* __restrict__ A1,
                                                float* __restrict__ xa2) {
  int bid = blockIdx.x; int b = bid >> 5, q = bid & 31;   // q: 128-col chunk of 4096
  __shared__ float At[64*68];                              // A1 transposed [j][c]
  __shared__ __align__(16) float Hs[64*132];
  int t = threadIdx.x;
#pragma unroll
  for (int p = 0; p < 16; ++p) {
    int m = t + p*256;                      // A1[c*64+j]
    At[(m & 63)*68 + (m >> 6)] = A1[m];
  }
  const float* hb = h + ((size_t)b*64)*4096 + q*128;
#pragma unroll
  for (int p = 0; p < 8; ++p) {
    int idx = t + p*256;                    // 2048 float4 tiles: 64 j x 32 f4
    int j = idx >> 5, f4 = idx & 31;
    *(float4*)&Hs[j*132 + f4*4] = *(const float4*)(hb + (size_t)j*4096 + f4*4);
  }
  __syncthreads();
  int tx = t & 31, ty = t >> 5;             // tx: f4 col, ty: 8-row c block
  float acc[8][4] = {};
  for (int j = 0; j < 64; ++j) {
    float a[8];
    *(float4*)&a[0] = *(const float4*)&At[j*68 + ty*8];
    *(float4*)&a[4] = *(const float4*)&At[j*68 + ty*8 + 4];
    float4 hv = *(const float4*)&Hs[j*132 + tx*4];
#pragma unroll
    for (int i = 0; i < 8; ++i) {
      acc[i][0] = fmaf(a[i], hv.x, acc[i][0]);
      acc[i][1] = fmaf(a[i], hv.y, acc[i][1]);
      acc[i][2] = fmaf(a[i], hv.z, acc[i][2]);
      acc[i][3] = fmaf(a[i], hv.w, acc[i][3]);
    }
  }
  float* outp = xa2 + (((size_t)b*64) << 12) + q*128 + tx*4;
#pragma unroll
  for (int i = 0; i < 8; ++i) {
    int c = ty*8 + i;
    *(float4*)(outp + ((size_t)c << 12)) =
        make_float4(acc[i][0], acc[i][1], acc[i][2], acc[i][3]);
  }
}

// ---- xa_cvt: xa2 [b][c][f][tp] f32 -> xahi/xalo [R][k=f] bf16, R=(b*32+tp)*64+c -----
__global__ __launch_bounds__(256) void xa_cvt(const float* __restrict__ xa2,
                                              unsigned short* __restrict__ xahi,
                                              unsigned short* __restrict__ xalo) {
  int bid = blockIdx.x;                      // 1024: b = bid>>5, cpair
  int b = bid >> 5, c0 = (bid & 31) * 2;
  __shared__ float xs[8192];                 // [c_l 2][f 128][tp 32]
  int t = threadIdx.x;
  const float* src = xa2 + ((size_t)(b*64 + c0) << 12);
#pragma unroll
  for (int p = 0; p < 8; ++p) {
    int idx = (t + p*256) * 4;
    *(float4*)&xs[idx] = *(const float4*)(src + idx);
  }
  __syncthreads();
  int row_l = t >> 2, fq = t & 3;            // row_l = c_l*32+tp
  int c_l = row_l >> 5, tp = row_l & 31;
  size_t R = ((size_t)b*32 + tp)*64 + c0 + c_l;
  const float* base = &xs[c_l*4096 + tp];
#pragma unroll
  for (int i = 0; i < 4; ++i) {
    int f8 = fq + 4*i;
    unsigned hp[4], lp[4];
#pragma unroll
    for (int jj = 0; jj < 4; ++jj) {
      unsigned short h0,l0,h1,l1;
      split_bf16(base[(f8*8 + 2*jj    )*32], h0, l0);
      split_bf16(base[(f8*8 + 2*jj + 1)*32], h1, l1);
      hp[jj] = (unsigned)h0 | ((unsigned)h1 << 16);
      lp[jj] = (unsigned)l0 | ((unsigned)l1 << 16);
    }
    *(uint4*)&xahi[R*128 + f8*8] = make_uint4(hp[0], hp[1], hp[2], hp[3]);
    *(uint4*)&xalo[R*128 + f8*8] = make_uint4(lp[0], lp[1], lp[2], lp[3]);
  }
}

// ---- gemm1m: y1 = prelu(bn(xa @ W1 + b1)) via bf16x3 MFMA; register prefetch --------
// block: 64 rows x 128 cols (colhalf), 4 waves; wave = 64 rows x 32 cols (4x2 tiles)
__global__ __launch_bounds__(256) void gemm1m(const unsigned short* __restrict__ xahi,
                                              const unsigned short* __restrict__ xalo,
                                              const unsigned short* __restrict__ Whi,
                                              const unsigned short* __restrict__ Wlo,
                                              const float* __restrict__ gc1b,
                                              const float* __restrict__ g1,
                                              const float* __restrict__ be1,
                                              const float* __restrict__ mu1,
                                              const float* __restrict__ v1,
                                              const float* __restrict__ pa1,
                                              const float* __restrict__ pw1,
                                              float* __restrict__ y1,
                                              float* __restrict__ dots2) {
  __shared__ unsigned short Ahs[64*40], Als[64*40];     // [row][k32 pad40]
  __shared__ unsigned short Bhs[128*40], Bls[128*40];   // [col][k32 pad40]
  __shared__ float dsum[64*4];
  int t = threadIdx.x;
  int row0 = blockIdx.x * 64;
  int colhalf = blockIdx.y;
  int w = t >> 6, l = t & 63, lr = l & 15, lg = l >> 4;
  // staging assignments (fixed per thread)
  int arow = t >> 2, akq = t & 3;
  size_t abase = (size_t)(row0 + arow)*128 + akq*8;
  int bcolb[2], bkq[2];
#pragma unroll
  for (int p = 0; p < 2; ++p) { int id = t + p*256; bcolb[p] = id >> 2; bkq[p] = id & 3; }
  size_t bbase[2];
#pragma unroll
  for (int p = 0; p < 2; ++p)
    bbase[p] = (size_t)(colhalf*128 + bcolb[p])*128 + bkq[p]*8;
  // initial prefetch (k0 = 0)
  uint4 pah = *(const uint4*)&xahi[abase];
  uint4 pal = *(const uint4*)&xalo[abase];
  uint4 pbh[2], pbl[2];
#pragma unroll
  for (int p = 0; p < 2; ++p) {
    pbh[p] = *(const uint4*)&Whi[bbase[p]];
    pbl[p] = *(const uint4*)&Wlo[bbase[p]];
  }
  f32x4_t acc[4][2] = {};
  for (int k0 = 0; k0 < 128; k0 += 32) {
    // stage from prefetched registers
    *(uint4*)&Ahs[arow*40 + akq*8] = pah;
    *(uint4*)&Als[arow*40 + akq*8] = pal;
#pragma unroll
    for (int p = 0; p < 2; ++p) {
      *(uint4*)&Bhs[bcolb[p]*40 + bkq[p]*8] = pbh[p];
      *(uint4*)&Bls[bcolb[p]*40 + bkq[p]*8] = pbl[p];
    }
    // prefetch next k-step (loads fly during barrier + MFMA)
    if (k0 + 32 < 128) {
      pah = *(const uint4*)&xahi[abase + k0 + 32];
      pal = *(const uint4*)&xalo[abase + k0 + 32];
#pragma unroll
      for (int p = 0; p < 2; ++p) {
        pbh[p] = *(const uint4*)&Whi[bbase[p] + k0 + 32];
        pbl[p] = *(const uint4*)&Wlo[bbase[p] + k0 + 32];
      }
    }
    __syncthreads();
    short8_t ah[4], al[4], bh[2], bl[2];
#pragma unroll
    for (int ss = 0; ss < 4; ++ss) {
      int off = (ss*16 + lr)*40 + lg*8;
      ah[ss] = *(const short8_t*)&Ahs[off];
      al[ss] = *(const short8_t*)&Als[off];
    }
#pragma unroll
    for (int t2 = 0; t2 < 2; ++t2) {
      int off = (w*32 + t2*16 + lr)*40 + lg*8;
      bh[t2] = *(const short8_t*)&Bhs[off];
      bl[t2] = *(const short8_t*)&Bls[off];
    }
#pragma unroll
    for (int ss = 0; ss < 4; ++ss)
#pragma unroll
      for (int t2 = 0; t2 < 2; ++t2) {
        acc[ss][t2] = __builtin_amdgcn_mfma_f32_16x16x32_bf16(ah[ss], bh[t2], acc[ss][t2], 0, 0, 0);
        acc[ss][t2] = __builtin_amdgcn_mfma_f32_16x16x32_bf16(al[ss], bh[t2], acc[ss][t2], 0, 0, 0);
        acc[ss][t2] = __builtin_amdgcn_mfma_f32_16x16x32_bf16(ah[ss], bl[t2], acc[ss][t2], 0, 0, 0);
      }
    __syncthreads();
  }
  // epilogue: BN + PReLU + y1 (f32) write + pool dot partials
  float sc_[2], sh_[2], pw_[2];
#pragma unroll
  for (int t2 = 0; t2 < 2; ++t2) {
    int col_g = colhalf*128 + w*32 + t2*16 + lr;
    float s = g1[col_g] * rsqrtf(v1[col_g] + 1e-5f);
    sc_[t2] = s;
    sh_[t2] = (gc1b[col_g] - mu1[col_g])*s + be1[col_g];
    pw_[t2] = pw1[col_g];
  }
  float a1v = pa1[0];
#pragma unroll
  for (int ss = 0; ss < 4; ++ss)
#pragma unroll
    for (int j = 0; j < 4; ++j) {
      int row_l = ss*16 + lg*4 + j;
      size_t R = (size_t)row0 + row_l;
      float d = 0.f;
#pragma unroll
      for (int t2 = 0; t2 < 2; ++t2) {
        float o = acc[ss][t2][j]*sc_[t2] + sh_[t2];
        o = o >= 0.f ? o : a1v*o;
        y1[R*NHID + colhalf*128 + w*32 + t2*16 + lr] = o;
        d += o * pw_[t2];
      }
      d += __shfl_xor(d, 1);
      d += __shfl_xor(d, 2);
      d += __shfl_xor(d, 4);
      d += __shfl_xor(d, 8);
      if (lr == 0) dsum[row_l*4 + w] = d;
    }
  __syncthreads();
  if (t < 64)
    dots2[((size_t)row0 + t)*2 + colhalf] =
        (dsum[t*4+0] + dsum[t*4+1]) + (dsum[t*4+2] + dsum[t*4+3]);
}

// ---- pool1s: scores = As1 @ dots + b; stable top-52; emit rowsrc/rowgate/nidx -------
__global__ __launch_bounds__(256) void pool1s(const float* __restrict__ dots2,
                                              const float* __restrict__ As1,
                                              const float* __restrict__ p1b,
                                              int* __restrict__ rowsrc,
                                              float* __restrict__ rowgate,
                                              int* __restrict__ nidx) {
  int g = blockIdx.x, t = threadIdx.x;
  __shared__ float As1s[64*65];
  __shared__ float sp[64], s[64];
  __shared__ int perm[K1_];
  __shared__ float gate[K1_];
  for (int i = t; i < 4096; i += 256)
    As1s[(i >> 6)*65 + (i & 63)] = As1[i];
  if (t < 64) sp[t] = dots2[(g*64 + t)*2] + dots2[(g*64 + t)*2 + 1];
  __syncthreads();
  if (t < 64) {
    float acc = p1b[0];
    for (int j = 0; j < 64; ++j) acc = fmaf(As1s[t*65 + j], sp[j], acc);
    s[t] = acc;
  }
  __syncthreads();
  if (t < 64) {
    float si = s[t];
    int rank = 0;
    for (int j = 0; j < 64; ++j) {
      float sj = s[j];
      rank += (sj > si) || (sj == si && j < t);
    }
    nidx[g*64 + t] = (rank < K1_) ? rank : -1;
    if (rank < K1_) { perm[rank] = t; gate[rank] = tanhf(si); }
  }
  __syncthreads();
  if (t < K1_) {
    rowsrc[g*K1_ + t]  = g*64 + perm[t];
    rowgate[g*K1_ + t] = gate[t];
  }
}

// ---- mega2f: per-graph fused layer 2; register-prefetch software pipeline -----------
__global__ __launch_bounds__(256) void mega2f(const float* __restrict__ y1,
                                              const int* __restrict__ rowsrc,
                                              const float* __restrict__ rowgate,
                                              const unsigned short* __restrict__ Whi,
                                              const unsigned short* __restrict__ Wmid,
                                              const unsigned short* __restrict__ Wlo,
                                              const int* __restrict__ ei,
                                              const float* __restrict__ ew,
                                              const int* __restrict__ nidx,
                                              const float* __restrict__ gc2b,
                                              const float* __restrict__ g2,
                                              const float* __restrict__ be2,
                                              const float* __restrict__ mu2,
                                              const float* __restrict__ v2,
                                              const float* __restrict__ pa2,
                                              const float* __restrict__ pw2,
                                              const float* __restrict__ p2b,
                                              float* __restrict__ out) {
  __shared__ __align__(16) char pool[50752];
  // phase-1 aliases (46080 B)
  unsigned short* Ahs = (unsigned short*)(pool);
  unsigned short* Ams = (unsigned short*)(pool + 5120);
  unsigned short* Als = (unsigned short*)(pool + 10240);
  unsigned short* Bhs = (unsigned short*)(pool + 15360);
  unsigned short* Bms = (unsigned short*)(pool + 25600);
  unsigned short* Bls = (unsigned short*)(pool + 35840);
  // phase-2 aliases (50752 B)
  float* xs   = (float*)(pool);            // 52*128*4 = 26624
  float* A2t  = (float*)(pool + 26624);    // [j 52][c 64] = 13312
  float* As2s = (float*)(pool + 39936);    // [c 52][j 52] = 10816
  float4* zpart = (float4*)(pool);         // 4096, aliases xs (dead by then)
  __shared__ float dg[K1_], dgs[K1_], dis[K1_], diss[K1_], d[K1_], s[K1_], gA[K1_];
  __shared__ int nm[C_], rankA[K1_];

  int t = threadIdx.x, g = blockIdx.x;
  int w = t >> 6, l = t & 63, lr = l & 15, lg = l >> 4;
  // ---------------- phase 1: MFMA with register prefetch ----------------
  int arow = t >> 2, akq = t & 3;
  int ar = (arow < K1_) ? arow : 0;
  size_t asrc = (size_t)rowsrc[g*K1_ + ar] * NHID + akq*8;
  float gt = rowgate[g*K1_ + ar];
  int bcolb[2], bkq[2];
#pragma unroll
  for (int p = 0; p < 2; ++p) { int id = t + p*256; bcolb[p] = id >> 2; bkq[p] = id & 3; }
  size_t bbase[2];
#pragma unroll
  for (int p = 0; p < 2; ++p) bbase[p] = (size_t)bcolb[p]*256 + bkq[p]*8;
  // initial prefetch (k0 = 0)
  float4 pav0 = *(const float4*)(y1 + asrc);
  float4 pav1 = *(const float4*)(y1 + asrc + 4);
  uint4 pbh[2], pbm[2], pbl[2];
#pragma unroll
  for (int p = 0; p < 2; ++p) {
    pbh[p] = *(const uint4*)&Whi [bbase[p]];
    pbm[p] = *(const uint4*)&Wmid[bbase[p]];
    pbl[p] = *(const uint4*)&Wlo [bbase[p]];
  }
  f32x4_t macc[4][2] = {};
  for (int k0 = 0; k0 < NHID; k0 += 32) {
    {   // stage A: gate + cheap split3 of prefetched values
      float e[8] = {pav0.x, pav0.y, pav0.z, pav0.w, pav1.x, pav1.y, pav1.z, pav1.w};
      unsigned hq[4], mq[4], lq[4];
#pragma unroll
      for (int jj = 0; jj < 4; ++jj) {
        unsigned short h0,m0,l0,h1,m1,l1;
        split3t_bf16(gt * e[2*jj],   h0, m0, l0);
        split3t_bf16(gt * e[2*jj+1], h1, m1, l1);
        hq[jj] = (unsigned)h0 | ((unsigned)h1 << 16);
        mq[jj] = (unsigned)m0 | ((unsigned)m1 << 16);
        lq[jj] = (unsigned)l0 | ((unsigned)l1 << 16);
      }
      *(uint4*)&Ahs[arow*40 + akq*8] = make_uint4(hq[0], hq[1], hq[2], hq[3]);
      *(uint4*)&Ams[arow*40 + akq*8] = make_uint4(mq[0], mq[1], mq[2], mq[3]);
      *(uint4*)&Als[arow*40 + akq*8] = make_uint4(lq[0], lq[1], lq[2], lq[3]);
    }
#pragma unroll
    for (int p = 0; p < 2; ++p) {   // stage B from prefetched registers
      *(uint4*)&Bhs[bcolb[p]*40 + bkq[p]*8] = pbh[p];
      *(uint4*)&Bms[bcolb[p]*40 + bkq[p]*8] = pbm[p];
      *(uint4*)&Bls[bcolb[p]*40 + bkq[p]*8] = pbl[p];
    }
    // prefetch next k-step (loads complete during barrier + MFMA phase)
    if (k0 + 32 < NHID) {
      pav0 = *(const float4*)(y1 + asrc + k0 + 32);
      pav1 = *(const float4*)(y1 + asrc + k0 + 32 + 4);
#pragma unroll
      for (int p = 0; p < 2; ++p) {
        pbh[p] = *(const uint4*)&Whi [bbase[p] + k0 + 32];
        pbm[p] = *(const uint4*)&Wmid[bbase[p] + k0 + 32];
        pbl[p] = *(const uint4*)&Wlo [bbase[p] + k0 + 32];
      }
    }
    __syncthreads();
    short8_t ah[4], am[4], al[4], bh[2], bm[2], bl[2];
#pragma unroll
    for (int ss = 0; ss < 4; ++ss) {
      int off = (ss*16 + lr)*40 + lg*8;
      ah[ss] = *(const short8_t*)&Ahs[off];
      am[ss] = *(const short8_t*)&Ams[off];
      al[ss] = *(const short8_t*)&Als[off];
    }
#pragma unroll
    for (int t2 = 0; t2 < 2; ++t2) {
      int off = (w*32 + t2*16 + lr)*40 + lg*8;
      bh[t2] = *(const short8_t*)&Bhs[off];
      bm[t2] = *(const short8_t*)&Bms[off];
      bl[t2] = *(const short8_t*)&Bls[off];
    }
#pragma unroll
    for (int ss = 0; ss < 4; ++ss)
#pragma unroll
      for (int t2 = 0; t2 < 2; ++t2) {
        macc[ss][t2] = __builtin_amdgcn_mfma_f32_16x16x32_bf16(ah[ss], bh[t2], macc[ss][t2], 0, 0, 0);
        macc[ss][t2] = __builtin_amdgcn_mfma_f32_16x16x32_bf16(ah[ss], bm[t2], macc[ss][t2], 0, 0, 0);
        macc[ss][t2] = __builtin_amdgcn_mfma_f32_16x16x32_bf16(am[ss], bh[t2], macc[ss][t2], 0, 0, 0);
        macc[ss][t2] = __builtin_amdgcn_mfma_f32_16x16x32_bf16(ah[ss], bl[t2], macc[ss][t2], 0, 0, 0);
        macc[ss][t2] = __builtin_amdgcn_mfma_f32_16x16x32_bf16(am[ss], bm[t2], macc[ss][t2], 0, 0, 0);
        macc[ss][t2] = __builtin_amdgcn_mfma_f32_16x16x32_bf16(al[ss], bh[t2], macc[ss][t2], 0, 0, 0);
      }
    __syncthreads();
  }
  // ---------------- phase 2 setup: xs <- macc; build A2/As2 ----------------
#pragma unroll
  for (int ss = 0; ss < 4; ++ss)
#pragma unroll
    for (int t2 = 0; t2 < 2; ++t2)
#pragma unroll
      for (int j = 0; j < 4; ++j) {
        int row_l = ss*16 + lg*4 + j;
        if (row_l < K1_)
          xs[row_l*128 + w*32 + t2*16 + lr] = macc[ss][t2][j];
      }
  for (int i = t; i < K1_*64; i += 256) A2t[i] = 0.f;
  for (int i = t; i < K1_*K1_; i += 256) As2s[i] = 0.f;
  if (t < C_) nm[t] = nidx[g*C_ + t];
  if (t < K1_) { dg[t] = 1.f; dgs[t] = 1.f; }
  int eR[2], eC[2]; float eW[2];
#pragma unroll
  for (int p = 0; p < 2; ++p) {
    int e = t + p*256;
    eR[p] = ei[e]; eC[p] = ei[E_ + e]; eW[p] = ew[e];
  }
  __syncthreads();
  int nr[2], nc[2]; bool val[2];
#pragma unroll
  for (int p = 0; p < 2; ++p) {
    nr[p] = nm[eR[p]]; nc[p] = nm[eC[p]];
    val[p] = (nr[p] >= 0) && (nc[p] >= 0);
    if (val[p]) { atomicAdd(&dg[nc[p]], eW[p]); atomicAdd(&dgs[nc[p]], 1.f); }
  }
  __syncthreads();
  if (t < K1_) { dis[t] = rsqrtf(dg[t]); diss[t] = rsqrtf(dgs[t]); }
  __syncthreads();
#pragma unroll
  for (int p = 0; p < 2; ++p) {
    if (val[p]) {
      atomicAdd(&A2t[nr[p]*64 + nc[p]],   dis[nr[p]] * eW[p] * dis[nc[p]]);
      atomicAdd(&As2s[nc[p]*K1_ + nr[p]], diss[nr[p]] * diss[nc[p]]);
    }
  }
  if (t < K1_) {
    atomicAdd(&A2t[t*64 + t],   dis[t]*dis[t]);
    atomicAdd(&As2s[t*K1_ + t], diss[t]*diss[t]);
  }
  __syncthreads();
  // ---------------- agg + BN + PReLU + dots ----------------
  int tx = t & 31, ty = t >> 5;
  float4 scv, shv, pwv;
  {
    int col = 4*tx;
    float4 gv = *(const float4*)(g2 + col);
    float4 vv = *(const float4*)(v2 + col);
    float4 bv = *(const float4*)(be2 + col);
    float4 mv = *(const float4*)(mu2 + col);
    float4 b0 = *(const float4*)(gc2b + col);
    scv.x = gv.x * rsqrtf(vv.x + 1e-5f); scv.y = gv.y * rsqrtf(vv.y + 1e-5f);
    scv.z = gv.z * rsqrtf(vv.z + 1e-5f); scv.w = gv.w * rsqrtf(vv.w + 1e-5f);
    shv = make_float4((b0.x - mv.x)*scv.x + bv.x, (b0.y - mv.y)*scv.y + bv.y,
                      (b0.z - mv.z)*scv.z + bv.z, (b0.w - mv.w)*scv.w + bv.w);
    pwv = *(const float4*)(pw2 + col);
  }
  float a2v = pa2[0];
  float aacc[8][4] = {};
  for (int j = 0; j < K1_; ++j) {
    float a[8];
    *(float4*)&a[0] = *(const float4*)&A2t[j*64 + ty*8];
    *(float4*)&a[4] = *(const float4*)&A2t[j*64 + ty*8 + 4];
    float4 xv = *(const float4*)&xs[j*128 + tx*4];
#pragma unroll
    for (int i = 0; i < 8; ++i) {
      aacc[i][0] = fmaf(a[i], xv.x, aacc[i][0]);
      aacc[i][1] = fmaf(a[i], xv.y, aacc[i][1]);
      aacc[i][2] = fmaf(a[i], xv.z, aacc[i][2]);
      aacc[i][3] = fmaf(a[i], xv.w, aacc[i][3]);
    }
  }
#pragma unroll
  for (int i = 0; i < 8; ++i) {
    int c = ty*8 + i;
    if (c < K1_) {
      float4 o;
      o.x = aacc[i][0]*scv.x + shv.x; o.y = aacc[i][1]*scv.y + shv.y;
      o.z = aacc[i][2]*scv.z + shv.z; o.w = aacc[i][3]*scv.w + shv.w;
      o.x = o.x >= 0.f ? o.x : a2v*o.x; o.y = o.y >= 0.f ? o.y : a2v*o.y;
      o.z = o.z >= 0.f ? o.z : a2v*o.z; o.w = o.w >= 0.f ? o.w : a2v*o.w;
      aacc[i][0] = o.x; aacc[i][1] = o.y; aacc[i][2] = o.z; aacc[i][3] = o.w;
      float dp = o.x*pwv.x + o.y*pwv.y + o.z*pwv.z + o.w*pwv.w;
      dp += __shfl_xor(dp, 1);
      dp += __shfl_xor(dp, 2);
      dp += __shfl_xor(dp, 4);
      dp += __shfl_xor(dp, 8);
      dp += __shfl_xor(dp, 16);
      if (tx == 0) d[c] = dp;
    }
  }
  __syncthreads();
  if (t < K1_) {
    float sv = p2b[0];
    for (int j = 0; j < K1_; ++j) sv = fmaf(As2s[t*K1_ + j], d[j], sv);
    s[t] = sv;
  }
  __syncthreads();
  if (t < K1_) {
    float si = s[t];
    int rank = 0;
    for (int j = 0; j < K1_; ++j) {
      float sj = s[j];
      rank += (sj > si) || (sj == si && j < t);
    }
    rankA[t] = rank;
    gA[t] = tanhf(si);
  }
  __syncthreads();
  // ---------------- rank-directed output + mean ----------------
  float4 zp = make_float4(0.f, 0.f, 0.f, 0.f);
#pragma unroll
  for (int i = 0; i < 8; ++i) {
    int c = ty*8 + i;
    if (c < K1_) {
      int r = rankA[c];
      if (r < K2_) {
        float gv = gA[c];
        float4 v = make_float4(aacc[i][0]*gv, aacc[i][1]*gv, aacc[i][2]*gv, aacc[i][3]*gv);
        *(float4*)(out + ((size_t)g*K2_ + r)*NOUT + 4*tx) = v;
        zp.x += v.x; zp.y += v.y; zp.z += v.z; zp.w += v.w;
      }
    }
  }
  __syncthreads();          // xs (aliased by zpart) fully dead
  zpart[ty*32 + tx] = zp;
  __syncthreads();
  if (t < 32) {
    float4 z = make_float4(0.f, 0.f, 0.f, 0.f);
#pragma unroll
    for (int k = 0; k < 8; ++k) {
      float4 v = zpart[k*32 + t];
      z.x += v.x; z.y += v.y; z.z += v.z; z.w += v.w;
    }
    const float inv = 1.0f / (float)K2_;
    z.x *= inv; z.y *= inv; z.z *= inv; z.w *= inv;
    *(float4*)(out + (size_t)G_*K2_*NOUT + (size_t)g*NOUT + 4*t) = z;
  }
}

extern "C" void kernel_launch(void* const* d_in, const int* in_sizes, int n_in,
                              void* d_out, int out_size, void* d_ws, size_t ws_size,
                              hipStream_t stream) {
  const float* h    = (const float*)d_in[0];
  const int*   ei   = (const int*)  d_in[1];
  const float* ew   = (const float*)d_in[2];
  const float* gc1w = (const float*)d_in[3];
  const float* gc1b = (const float*)d_in[4];
  const float* bn1g = (const float*)d_in[5];
  const float* bn1b = (const float*)d_in[6];
  const float* bn1m = (const float*)d_in[7];
  const float* bn1v = (const float*)d_in[8];
  const float* pr1a = (const float*)d_in[9];
  const float* p1w  = (const float*)d_in[10];
  const float* p1b  = (const float*)d_in[11];
  const float* gc2w = (const float*)d_in[12];
  const float* gc2b = (const float*)d_in[13];
  const float* bn2g = (const float*)d_in[14];
  const float* bn2b = (const float*)d_in[15];
  const float* bn2m = (const float*)d_in[16];
  const float* bn2v = (const float*)d_in[17];
  const float* pr2a = (const float*)d_in[18];
  const float* p2w  = (const float*)d_in[19];
  const float* p2b  = (const float*)d_in[20];

  float* w = (float*)d_ws;
  // float offsets
  float*          A1      = w;                               // 4096
  float*          As1     = w + 4096;                        // 4096
  float*          dots2   = w + 8192;                        // 131072
  int*            nidx    = (int*)(w + 139264);              // 65536
  int*            rowsrc  = (int*)(w + 204800);              // 53248
  float*          rowgate = w + 258048;                      // 53248
  unsigned short* W1thi   = (unsigned short*)(w + 311296);   // 16384 fl
  unsigned short* W1tlo   = (unsigned short*)(w + 327680);   // 16384 fl
  unsigned short* W2thi   = (unsigned short*)(w + 344064);   // 16384 fl
  unsigned short* W2tmid  = (unsigned short*)(w + 360448);   // 16384 fl
  unsigned short* W2tlo   = (unsigned short*)(w + 376832);   // 16384 fl
  float*          xa2     = w + 393216;                      // 8388608
  unsigned short* xahi    = (unsigned short*)(w + 8781824);  // 4194304 fl
  unsigned short* xalo    = (unsigned short*)(w + 12976128); // 4194304 fl
  float*          y1      = w + 17170432;                    // 16777216 fl -> 33947648

  prep_all<<<129, 256, 0, stream>>>(ei, ew, gc1w, gc2w, A1, As1,
                                    W1thi, W1tlo, W2thi, W2tmid, W2tlo);
  preagg_b<<<1024, 256, 0, stream>>>(h, A1, xa2);
  xa_cvt<<<1024, 256, 0, stream>>>(xa2, xahi, xalo);
  gemm1m<<<dim3(1024, 2), 256, 0, stream>>>(xahi, xalo, W1thi, W1tlo, gc1b,
                                            bn1g, bn1b, bn1m, bn1v, pr1a, p1w,
                                            y1, dots2);
  pool1s<<<G_, 256, 0, stream>>>(dots2, As1, p1b, rowsrc, rowgate, nidx);
  mega2f<<<G_, 256, 0, stream>>>(y1, rowsrc, rowgate, W2thi, W2tmid, W2tlo,
                                 ei, ew, nidx, gc2b, bn2g, bn2b, bn2m, bn2v,
                                 pr2a, p2w, p2b, (float*)d_out);
}

// Round 18
// 132.982 us; speedup vs baseline: 1.2521x; 1.2521x over previous
//
#include <hip/hip_runtime.h>
#include <math.h>

#define B_   32
#define C_   64
#define F_   128
#define TP_  32
#define G_   (B_*TP_)      // 1024 graphs
#define NHID 256
#define NOUT 128
#define E_   512
#define K1_  52            // ceil(0.8*64)
#define K2_  42            // ceil(0.8*52)

typedef __attribute__((ext_vector_type(8))) short short8_t;   // 8 bf16 (4 VGPR)
typedef __attribute__((ext_vector_type(4))) float f32x4_t;

__device__ __forceinline__ void split_bf16(float v, unsigned short &h, unsigned short &l) {
  unsigned u = __float_as_uint(v);
  unsigned hb = (u + 0x7FFFu + ((u >> 16) & 1u)) & 0xFFFF0000u;  // RNE bf16 of v
  float hf = __uint_as_float(hb);
  float r = v - hf;                                              // exact in f32
  unsigned ur = __float_as_uint(r);
  unsigned lb = (ur + 0x7FFFu + ((ur >> 16) & 1u)) >> 16;        // RNE bf16 of r
  h = (unsigned short)(hb >> 16);
  l = (unsigned short)lb;
}

// RNE 3-limb split (used for weights, one-time prep)
__device__ __forceinline__ void split3_bf16(float v, unsigned short &h,
                                            unsigned short &m, unsigned short &l) {
  unsigned u = __float_as_uint(v);
  unsigned hb = (u + 0x7FFFu + ((u >> 16) & 1u)) & 0xFFFF0000u;
  float hf = __uint_as_float(hb);
  float r1 = v - hf;                                             // exact
  unsigned u1 = __float_as_uint(r1);
  unsigned mb = (u1 + 0x7FFFu + ((u1 >> 16) & 1u)) & 0xFFFF0000u;
  float mf = __uint_as_float(mb);
  float r2 = r1 - mf;                                            // exact
  unsigned u2 = __float_as_uint(r2);
  unsigned lb = (u2 + 0x7FFFu + ((u2 >> 16) & 1u)) >> 16;
  h = (unsigned short)(hb >> 16);
  m = (unsigned short)(mb >> 16);
  l = (unsigned short)lb;
}

// cheap 3-limb split: trunc hi/mid (exact remainders), RNE last limb. err <= 2^-22|v|
__device__ __forceinline__ void split3t_bf16(float v, unsigned short &h,
                                             unsigned short &m, unsigned short &l) {
  unsigned u = __float_as_uint(v);
  float hf = __uint_as_float(u & 0xFFFF0000u);
  float r1 = v - hf;                                             // exact
  unsigned u1 = __float_as_uint(r1);
  float mf = __uint_as_float(u1 & 0xFFFF0000u);
  float r2 = r1 - mf;                                            // exact
  unsigned u2 = __float_as_uint(r2);
  unsigned lb = (u2 + 0x7FFFu + ((u2 >> 16) & 1u)) >> 16;        // RNE
  h = (unsigned short)(u >> 16);
  m = (unsigned short)(u1 >> 16);
  l = (unsigned short)lb;
}

// ---- prep_all: block 0 -> build A1/As1; blocks 1..64 -> w1prep; 65..128 -> w2prep ---
__global__ __launch_bounds__(256) void prep_all(const int* __restrict__ ei,
                                                const float* __restrict__ ew,
                                                const float* __restrict__ W1,
                                                const float* __restrict__ W2,
                                                float* __restrict__ A1,
                                                float* __restrict__ As1,
                                                unsigned short* __restrict__ W1hi,
                                                unsigned short* __restrict__ W1lo,
                                                unsigned short* __restrict__ W2hi,
                                                unsigned short* __restrict__ W2mid,
                                                unsigned short* __restrict__ W2lo) {
  int t = threadIdx.x;
  int blk = blockIdx.x;
  if (blk == 0) {
    __shared__ float A1s[C_*C_], As1s[C_*C_];
    __shared__ float dg[C_], dgs[C_], dis[C_], diss[C_];
    for (int i = t; i < C_*C_; i += 256) { A1s[i] = 0.f; As1s[i] = 0.f; }
    if (t < C_) { dg[t] = 1.f; dgs[t] = 1.f; }   // self-loop weight 1
    int r0[2], c0[2]; float w0[2];
#pragma unroll
    for (int p = 0; p < 2; ++p) {
      int e = t + p*256;
      r0[p] = ei[e]; c0[p] = ei[E_ + e]; w0[p] = ew[e];
    }
    __syncthreads();
#pragma unroll
    for (int p = 0; p < 2; ++p) {
      atomicAdd(&dg[c0[p]], w0[p]);
      atomicAdd(&dgs[c0[p]], 1.f);
    }
    __syncthreads();
    if (t < C_) { dis[t] = rsqrtf(dg[t]); diss[t] = rsqrtf(dgs[t]); }
    __syncthreads();
#pragma unroll
    for (int p = 0; p < 2; ++p) {
      int r = r0[p], c = c0[p];
      atomicAdd(&A1s[c*C_ + r],  dis[r] * w0[p] * dis[c]);
      atomicAdd(&As1s[c*C_ + r], diss[r] * diss[c]);
    }
    if (t < C_) {
      atomicAdd(&A1s[t*C_ + t],  dis[t] * dis[t]);
      atomicAdd(&As1s[t*C_ + t], diss[t] * diss[t]);
    }
    __syncthreads();
    for (int i = t; i < C_*C_; i += 256) { A1[i] = A1s[i]; As1[i] = As1s[i]; }
  } else if (blk <= 64) {
    int tid = (blk - 1)*256 + t;              // 16384 threads, 2 k's each
    int col = tid >> 6, k2 = tid & 63;
    float v0 = W1[(size_t)(2*k2)*NHID + col];
    float v1 = W1[(size_t)(2*k2+1)*NHID + col];
    unsigned short h0,l0,h1,l1;
    split_bf16(v0, h0, l0);
    split_bf16(v1, h1, l1);
    *(unsigned*)&W1hi[(size_t)col*128 + 2*k2] = (unsigned)h0 | ((unsigned)h1 << 16);
    *(unsigned*)&W1lo[(size_t)col*128 + 2*k2] = (unsigned)l0 | ((unsigned)l1 << 16);
  } else {
    int tid = (blk - 65)*256 + t;             // 16384 threads, 2 k's each
    int col = tid >> 7, k2 = tid & 127;
    float v0 = W2[(size_t)(2*k2)*NOUT + col];
    float v1 = W2[(size_t)(2*k2+1)*NOUT + col];
    unsigned short h0,m0,l0,h1,m1,l1;
    split3_bf16(v0, h0, m0, l0);
    split3_bf16(v1, h1, m1, l1);
    *(unsigned*)&W2hi [(size_t)col*256 + 2*k2] = (unsigned)h0 | ((unsigned)h1 << 16);
    *(unsigned*)&W2mid[(size_t)col*256 + 2*k2] = (unsigned)m0 | ((unsigned)m1 << 16);
    *(unsigned*)&W2lo [(size_t)col*256 + 2*k2] = (unsigned)l0 | ((unsigned)l1 << 16);
  }
}

// ---- preagg: xa2[b,c,f,tp] = sum_j A1[c,j] * h[b,j,f,tp]  (per-b, (f,tp) cols) ------
__global__ __launch_bounds__(256) void preagg_b(const float* __restrict__ h,
                                                const float* __restrict__ A1,
                                                float* __restrict__ xa2) {
  int bid = blockIdx.x; int b = bid >> 5, q = bid & 31;   // q: 128-col chunk of 4096
  __shared__ float At[64*68];                              // A1 transposed [j][c]
  __shared__ __align__(16) float Hs[64*132];
  int t = threadIdx.x;
#pragma unroll
  for (int p = 0; p < 16; ++p) {
    int m = t + p*256;                      // A1[c*64+j]
    At[(m & 63)*68 + (m >> 6)] = A1[m];
  }
  const float* hb = h + ((size_t)b*64)*4096 + q*128;
#pragma unroll
  for (int p = 0; p < 8; ++p) {
    int idx = t + p*256;                    // 2048 float4 tiles: 64 j x 32 f4
    int j = idx >> 5, f4 = idx & 31;
    *(float4*)&Hs[j*132 + f4*4] = *(const float4*)(hb + (size_t)j*4096 + f4*4);
  }
  __syncthreads();
  int tx = t & 31, ty = t >> 5;             // tx: f4 col, ty: 8-row c block
  float acc[8][4] = {};
  for (int j = 0; j < 64; ++j) {
    float a[8];
    *(float4*)&a[0] = *(const float4*)&At[j*68 + ty*8];
    *(float4*)&a[4] = *(const float4*)&At[j*68 + ty*8 + 4];
    float4 hv = *(const float4*)&Hs[j*132 + tx*4];
#pragma unroll
    for (int i = 0; i < 8; ++i) {
      acc[i][0] = fmaf(a[i], hv.x, acc[i][0]);
      acc[i][1] = fmaf(a[i], hv.y, acc[i][1]);
      acc[i][2] = fmaf(a[i], hv.z, acc[i][2]);
      acc[i][3] = fmaf(a[i], hv.w, acc[i][3]);
    }
  }
  float* outp = xa2 + (((size_t)b*64) << 12) + q*128 + tx*4;
#pragma unroll
  for (int i = 0; i < 8; ++i) {
    int c = ty*8 + i;
    *(float4*)(outp + ((size_t)c << 12)) =
        make_float4(acc[i][0], acc[i][1], acc[i][2], acc[i][3]);
  }
}

// ---- xa_cvt: xa2 [b][c][f][tp] f32 -> xahi/xalo [R][k=f] bf16, R=(b*32+tp)*64+c -----
__global__ __launch_bounds__(256) void xa_cvt(const float* __restrict__ xa2,
                                              unsigned short* __restrict__ xahi,
                                              unsigned short* __restrict__ xalo) {
  int bid = blockIdx.x;                      // 1024: b = bid>>5, cpair
  int b = bid >> 5, c0 = (bid & 31) * 2;
  __shared__ float xs[8192];                 // [c_l 2][f 128][tp 32]
  int t = threadIdx.x;
  const float* src = xa2 + ((size_t)(b*64 + c0) << 12);
#pragma unroll
  for (int p = 0; p < 8; ++p) {
    int idx = (t + p*256) * 4;
    *(float4*)&xs[idx] = *(const float4*)(src + idx);
  }
  __syncthreads();
  int row_l = t >> 2, fq = t & 3;            // row_l = c_l*32+tp
  int c_l = row_l >> 5, tp = row_l & 31;
  size_t R = ((size_t)b*32 + tp)*64 + c0 + c_l;
  const float* base = &xs[c_l*4096 + tp];
#pragma unroll
  for (int i = 0; i < 4; ++i) {
    int f8 = fq + 4*i;
    unsigned hp[4], lp[4];
#pragma unroll
    for (int jj = 0; jj < 4; ++jj) {
      unsigned short h0,l0,h1,l1;
      split_bf16(base[(f8*8 + 2*jj    )*32], h0, l0);
      split_bf16(base[(f8*8 + 2*jj + 1)*32], h1, l1);
      hp[jj] = (unsigned)h0 | ((unsigned)h1 << 16);
      lp[jj] = (unsigned)l0 | ((unsigned)l1 << 16);
    }
    *(uint4*)&xahi[R*128 + f8*8] = make_uint4(hp[0], hp[1], hp[2], hp[3]);
    *(uint4*)&xalo[R*128 + f8*8] = make_uint4(lp[0], lp[1], lp[2], lp[3]);
  }
}

// ---- gemm1m: y1 = prelu(bn(xa @ W1 + b1)) via bf16x3 MFMA; y1 out as f32 ------------
// block: 64 rows x 128 cols (colhalf), 4 waves; wave = 64 rows x 32 cols (4x2 tiles)
__global__ __launch_bounds__(256) void gemm1m(const unsigned short* __restrict__ xahi,
                                              const unsigned short* __restrict__ xalo,
                                              const unsigned short* __restrict__ Whi,
                                              const unsigned short* __restrict__ Wlo,
                                              const float* __restrict__ gc1b,
                                              const float* __restrict__ g1,
                                              const float* __restrict__ be1,
                                              const float* __restrict__ mu1,
                                              const float* __restrict__ v1,
                                              const float* __restrict__ pa1,
                                              const float* __restrict__ pw1,
                                              float* __restrict__ y1,
                                              float* __restrict__ dots2) {
  __shared__ unsigned short Ahs[64*40], Als[64*40];     // [row][k32 pad40]
  __shared__ unsigned short Bhs[128*40], Bls[128*40];   // [col][k32 pad40]
  __shared__ float dsum[64*4];
  int t = threadIdx.x;
  int row0 = blockIdx.x * 64;
  int colhalf = blockIdx.y;
  int w = t >> 6, l = t & 63, lr = l & 15, lg = l >> 4;
  f32x4_t acc[4][2] = {};
  for (int k0 = 0; k0 < 128; k0 += 32) {
    {   // stage A: 64 rows x 32 k, 16B chunk per thread per plane
      int row = t >> 2, kq = t & 3;
      size_t src = (size_t)(row0 + row)*128 + k0 + kq*8;
      *(uint4*)&Ahs[row*40 + kq*8] = *(const uint4*)&xahi[src];
      *(uint4*)&Als[row*40 + kq*8] = *(const uint4*)&xalo[src];
    }
#pragma unroll
    for (int p = 0; p < 2; ++p) {   // stage B: 128 cols x 32 k
      int id = t + p*256;
      int colb = id >> 2, kq = id & 3;
      size_t src = (size_t)(colhalf*128 + colb)*128 + k0 + kq*8;
      *(uint4*)&Bhs[colb*40 + kq*8] = *(const uint4*)&Whi[src];
      *(uint4*)&Bls[colb*40 + kq*8] = *(const uint4*)&Wlo[src];
    }
    __syncthreads();
    short8_t ah[4], al[4], bh[2], bl[2];
#pragma unroll
    for (int ss = 0; ss < 4; ++ss) {
      int off = (ss*16 + lr)*40 + lg*8;
      ah[ss] = *(const short8_t*)&Ahs[off];
      al[ss] = *(const short8_t*)&Als[off];
    }
#pragma unroll
    for (int t2 = 0; t2 < 2; ++t2) {
      int off = (w*32 + t2*16 + lr)*40 + lg*8;
      bh[t2] = *(const short8_t*)&Bhs[off];
      bl[t2] = *(const short8_t*)&Bls[off];
    }
#pragma unroll
    for (int ss = 0; ss < 4; ++ss)
#pragma unroll
      for (int t2 = 0; t2 < 2; ++t2) {
        acc[ss][t2] = __builtin_amdgcn_mfma_f32_16x16x32_bf16(ah[ss], bh[t2], acc[ss][t2], 0, 0, 0);
        acc[ss][t2] = __builtin_amdgcn_mfma_f32_16x16x32_bf16(al[ss], bh[t2], acc[ss][t2], 0, 0, 0);
        acc[ss][t2] = __builtin_amdgcn_mfma_f32_16x16x32_bf16(ah[ss], bl[t2], acc[ss][t2], 0, 0, 0);
      }
    __syncthreads();
  }
  // epilogue: BN + PReLU + y1 (f32) write + pool dot partials
  float sc_[2], sh_[2], pw_[2];
#pragma unroll
  for (int t2 = 0; t2 < 2; ++t2) {
    int col_g = colhalf*128 + w*32 + t2*16 + lr;
    float s = g1[col_g] * rsqrtf(v1[col_g] + 1e-5f);
    sc_[t2] = s;
    sh_[t2] = (gc1b[col_g] - mu1[col_g])*s + be1[col_g];
    pw_[t2] = pw1[col_g];
  }
  float a1v = pa1[0];
#pragma unroll
  for (int ss = 0; ss < 4; ++ss)
#pragma unroll
    for (int j = 0; j < 4; ++j) {
      int row_l = ss*16 + lg*4 + j;
      size_t R = (size_t)row0 + row_l;
      float d = 0.f;
#pragma unroll
      for (int t2 = 0; t2 < 2; ++t2) {
        float o = acc[ss][t2][j]*sc_[t2] + sh_[t2];
        o = o >= 0.f ? o : a1v*o;
        y1[R*NHID + colhalf*128 + w*32 + t2*16 + lr] = o;
        d += o * pw_[t2];
      }
      d += __shfl_xor(d, 1);
      d += __shfl_xor(d, 2);
      d += __shfl_xor(d, 4);
      d += __shfl_xor(d, 8);
      if (lr == 0) dsum[row_l*4 + w] = d;
    }
  __syncthreads();
  if (t < 64)
    dots2[((size_t)row0 + t)*2 + colhalf] =
        (dsum[t*4+0] + dsum[t*4+1]) + (dsum[t*4+2] + dsum[t*4+3]);
}

// ---- pool1s: scores = As1 @ dots + b; stable top-52; emit rowsrc/rowgate/nidx -------
__global__ __launch_bounds__(256) void pool1s(const float* __restrict__ dots2,
                                              const float* __restrict__ As1,
                                              const float* __restrict__ p1b,
                                              int* __restrict__ rowsrc,
                                              float* __restrict__ rowgate,
                                              int* __restrict__ nidx) {
  int g = blockIdx.x, t = threadIdx.x;
  __shared__ float As1s[64*65];
  __shared__ float sp[64], s[64];
  __shared__ int perm[K1_];
  __shared__ float gate[K1_];
  for (int i = t; i < 4096; i += 256)
    As1s[(i >> 6)*65 + (i & 63)] = As1[i];
  if (t < 64) sp[t] = dots2[(g*64 + t)*2] + dots2[(g*64 + t)*2 + 1];
  __syncthreads();
  if (t < 64) {
    float acc = p1b[0];
    for (int j = 0; j < 64; ++j) acc = fmaf(As1s[t*65 + j], sp[j], acc);
    s[t] = acc;
  }
  __syncthreads();
  if (t < 64) {
    float si = s[t];
    int rank = 0;
    for (int j = 0; j < 64; ++j) {
      float sj = s[j];
      rank += (sj > si) || (sj == si && j < t);
    }
    nidx[g*64 + t] = (rank < K1_) ? rank : -1;
    if (rank < K1_) { perm[rank] = t; gate[rank] = tanhf(si); }
  }
  __syncthreads();
  if (t < K1_) {
    rowsrc[g*K1_ + t]  = g*64 + perm[t];
    rowgate[g*K1_ + t] = gate[t];
  }
}

// ---- mega2f: per-graph fused layer 2 (round-16 validated structure) -----------------
__global__ __launch_bounds__(256) void mega2f(const float* __restrict__ y1,
                                              const int* __restrict__ rowsrc,
                                              const float* __restrict__ rowgate,
                                              const unsigned short* __restrict__ Whi,
                                              const unsigned short* __restrict__ Wmid,
                                              const unsigned short* __restrict__ Wlo,
                                              const int* __restrict__ ei,
                                              const float* __restrict__ ew,
                                              const int* __restrict__ nidx,
                                              const float* __restrict__ gc2b,
                                              const float* __restrict__ g2,
                                              const float* __restrict__ be2,
                                              const float* __restrict__ mu2,
                                              const float* __restrict__ v2,
                                              const float* __restrict__ pa2,
                                              const float* __restrict__ pw2,
                                              const float* __restrict__ p2b,
                                              float* __restrict__ out) {
  __shared__ __align__(16) char pool[50752];
  // phase-1 aliases (46080 B)
  unsigned short* Ahs = (unsigned short*)(pool);
  unsigned short* Ams = (unsigned short*)(pool + 5120);
  unsigned short* Als = (unsigned short*)(pool + 10240);
  unsigned short* Bhs = (unsigned short*)(pool + 15360);
  unsigned short* Bms = (unsigned short*)(pool + 25600);
  unsigned short* Bls = (unsigned short*)(pool + 35840);
  // phase-2 aliases (50752 B)
  float* xs   = (float*)(pool);            // 52*128*4 = 26624
  float* A2t  = (float*)(pool + 26624);    // [j 52][c 64] = 13312
  float* As2s = (float*)(pool + 39936);    // [c 52][j 52] = 10816
  float4* zpart = (float4*)(pool);         // 4096, aliases xs (dead by then)
  __shared__ float dg[K1_], dgs[K1_], dis[K1_], diss[K1_], d[K1_], s[K1_], gA[K1_];
  __shared__ int nm[C_], rankA[K1_];

  int t = threadIdx.x, g = blockIdx.x;
  int w = t >> 6, l = t & 63, lr = l & 15, lg = l >> 4;
  // ---------------- phase 1: MFMA ----------------
  int arow = t >> 2, akq = t & 3;
  int ar = (arow < K1_) ? arow : 0;
  size_t asrc = (size_t)rowsrc[g*K1_ + ar] * NHID;
  float gt = rowgate[g*K1_ + ar];
  f32x4_t macc[4][2] = {};
  for (int k0 = 0; k0 < NHID; k0 += 32) {
    {   // stage A: gather f32, gate, cheap split3 into limb planes
      const float* src = y1 + asrc + k0 + akq*8;
      float4 v0 = *(const float4*)(src);
      float4 v1 = *(const float4*)(src + 4);
      float e[8] = {v0.x, v0.y, v0.z, v0.w, v1.x, v1.y, v1.z, v1.w};
      unsigned hq[4], mq[4], lq[4];
#pragma unroll
      for (int jj = 0; jj < 4; ++jj) {
        unsigned short h0,m0,l0,h1,m1,l1;
        split3t_bf16(gt * e[2*jj],   h0, m0, l0);
        split3t_bf16(gt * e[2*jj+1], h1, m1, l1);
        hq[jj] = (unsigned)h0 | ((unsigned)h1 << 16);
        mq[jj] = (unsigned)m0 | ((unsigned)m1 << 16);
        lq[jj] = (unsigned)l0 | ((unsigned)l1 << 16);
      }
      *(uint4*)&Ahs[arow*40 + akq*8] = make_uint4(hq[0], hq[1], hq[2], hq[3]);
      *(uint4*)&Ams[arow*40 + akq*8] = make_uint4(mq[0], mq[1], mq[2], mq[3]);
      *(uint4*)&Als[arow*40 + akq*8] = make_uint4(lq[0], lq[1], lq[2], lq[3]);
    }
#pragma unroll
    for (int p = 0; p < 2; ++p) {   // stage B: 128 cols x 32 k, 3 planes
      int id = t + p*256;
      int colb = id >> 2, kq = id & 3;
      size_t src = (size_t)colb*256 + k0 + kq*8;
      *(uint4*)&Bhs[colb*40 + kq*8] = *(const uint4*)&Whi[src];
      *(uint4*)&Bms[colb*40 + kq*8] = *(const uint4*)&Wmid[src];
      *(uint4*)&Bls[colb*40 + kq*8] = *(const uint4*)&Wlo[src];
    }
    __syncthreads();
    short8_t ah[4], am[4], al[4], bh[2], bm[2], bl[2];
#pragma unroll
    for (int ss = 0; ss < 4; ++ss) {
      int off = (ss*16 + lr)*40 + lg*8;
      ah[ss] = *(const short8_t*)&Ahs[off];
      am[ss] = *(const short8_t*)&Ams[off];
      al[ss] = *(const short8_t*)&Als[off];
    }
#pragma unroll
    for (int t2 = 0; t2 < 2; ++t2) {
      int off = (w*32 + t2*16 + lr)*40 + lg*8;
      bh[t2] = *(const short8_t*)&Bhs[off];
      bm[t2] = *(const short8_t*)&Bms[off];
      bl[t2] = *(const short8_t*)&Bls[off];
    }
#pragma unroll
    for (int ss = 0; ss < 4; ++ss)
#pragma unroll
      for (int t2 = 0; t2 < 2; ++t2) {
        macc[ss][t2] = __builtin_amdgcn_mfma_f32_16x16x32_bf16(ah[ss], bh[t2], macc[ss][t2], 0, 0, 0);
        macc[ss][t2] = __builtin_amdgcn_mfma_f32_16x16x32_bf16(ah[ss], bm[t2], macc[ss][t2], 0, 0, 0);
        macc[ss][t2] = __builtin_amdgcn_mfma_f32_16x16x32_bf16(am[ss], bh[t2], macc[ss][t2], 0, 0, 0);
        macc[ss][t2] = __builtin_amdgcn_mfma_f32_16x16x32_bf16(ah[ss], bl[t2], macc[ss][t2], 0, 0, 0);
        macc[ss][t2] = __builtin_amdgcn_mfma_f32_16x16x32_bf16(am[ss], bm[t2], macc[ss][t2], 0, 0, 0);
        macc[ss][t2] = __builtin_amdgcn_mfma_f32_16x16x32_bf16(al[ss], bh[t2], macc[ss][t2], 0, 0, 0);
      }
    __syncthreads();
  }
  // ---------------- phase 2 setup: xs <- macc; build A2/As2 ----------------
#pragma unroll
  for (int ss = 0; ss < 4; ++ss)
#pragma unroll
    for (int t2 = 0; t2 < 2; ++t2)
#pragma unroll
      for (int j = 0; j < 4; ++j) {
        int row_l = ss*16 + lg*4 + j;
        if (row_l < K1_)
          xs[row_l*128 + w*32 + t2*16 + lr] = macc[ss][t2][j];
      }
  for (int i = t; i < K1_*64; i += 256) A2t[i] = 0.f;
  for (int i = t; i < K1_*K1_; i += 256) As2s[i] = 0.f;
  if (t < C_) nm[t] = nidx[g*C_ + t];
  if (t < K1_) { dg[t] = 1.f; dgs[t] = 1.f; }
  int eR[2], eC[2]; float eW[2];
#pragma unroll
  for (int p = 0; p < 2; ++p) {
    int e = t + p*256;
    eR[p] = ei[e]; eC[p] = ei[E_ + e]; eW[p] = ew[e];
  }
  __syncthreads();
  int nr[2], nc[2]; bool val[2];
#pragma unroll
  for (int p = 0; p < 2; ++p) {
    nr[p] = nm[eR[p]]; nc[p] = nm[eC[p]];
    val[p] = (nr[p] >= 0) && (nc[p] >= 0);
    if (val[p]) { atomicAdd(&dg[nc[p]], eW[p]); atomicAdd(&dgs[nc[p]], 1.f); }
  }
  __syncthreads();
  if (t < K1_) { dis[t] = rsqrtf(dg[t]); diss[t] = rsqrtf(dgs[t]); }
  __syncthreads();
#pragma unroll
  for (int p = 0; p < 2; ++p) {
    if (val[p]) {
      atomicAdd(&A2t[nr[p]*64 + nc[p]],   dis[nr[p]] * eW[p] * dis[nc[p]]);
      atomicAdd(&As2s[nc[p]*K1_ + nr[p]], diss[nr[p]] * diss[nc[p]]);
    }
  }
  if (t < K1_) {
    atomicAdd(&A2t[t*64 + t],   dis[t]*dis[t]);
    atomicAdd(&As2s[t*K1_ + t], diss[t]*diss[t]);
  }
  __syncthreads();
  // ---------------- agg + BN + PReLU + dots ----------------
  int tx = t & 31, ty = t >> 5;
  float4 scv, shv, pwv;
  {
    int col = 4*tx;
    float4 gv = *(const float4*)(g2 + col);
    float4 vv = *(const float4*)(v2 + col);
    float4 bv = *(const float4*)(be2 + col);
    float4 mv = *(const float4*)(mu2 + col);
    float4 b0 = *(const float4*)(gc2b + col);
    scv.x = gv.x * rsqrtf(vv.x + 1e-5f); scv.y = gv.y * rsqrtf(vv.y + 1e-5f);
    scv.z = gv.z * rsqrtf(vv.z + 1e-5f); scv.w = gv.w * rsqrtf(vv.w + 1e-5f);
    shv = make_float4((b0.x - mv.x)*scv.x + bv.x, (b0.y - mv.y)*scv.y + bv.y,
                      (b0.z - mv.z)*scv.z + bv.z, (b0.w - mv.w)*scv.w + bv.w);
    pwv = *(const float4*)(pw2 + col);
  }
  float a2v = pa2[0];
  float aacc[8][4] = {};
  for (int j = 0; j < K1_; ++j) {
    float a[8];
    *(float4*)&a[0] = *(const float4*)&A2t[j*64 + ty*8];
    *(float4*)&a[4] = *(const float4*)&A2t[j*64 + ty*8 + 4];
    float4 xv = *(const float4*)&xs[j*128 + tx*4];
#pragma unroll
    for (int i = 0; i < 8; ++i) {
      aacc[i][0] = fmaf(a[i], xv.x, aacc[i][0]);
      aacc[i][1] = fmaf(a[i], xv.y, aacc[i][1]);
      aacc[i][2] = fmaf(a[i], xv.z, aacc[i][2]);
      aacc[i][3] = fmaf(a[i], xv.w, aacc[i][3]);
    }
  }
#pragma unroll
  for (int i = 0; i < 8; ++i) {
    int c = ty*8 + i;
    if (c < K1_) {
      float4 o;
      o.x = aacc[i][0]*scv.x + shv.x; o.y = aacc[i][1]*scv.y + shv.y;
      o.z = aacc[i][2]*scv.z + shv.z; o.w = aacc[i][3]*scv.w + shv.w;
      o.x = o.x >= 0.f ? o.x : a2v*o.x; o.y = o.y >= 0.f ? o.y : a2v*o.y;
      o.z = o.z >= 0.f ? o.z : a2v*o.z; o.w = o.w >= 0.f ? o.w : a2v*o.w;
      aacc[i][0] = o.x; aacc[i][1] = o.y; aacc[i][2] = o.z; aacc[i][3] = o.w;
      float dp = o.x*pwv.x + o.y*pwv.y + o.z*pwv.z + o.w*pwv.w;
      dp += __shfl_xor(dp, 1);
      dp += __shfl_xor(dp, 2);
      dp += __shfl_xor(dp, 4);
      dp += __shfl_xor(dp, 8);
      dp += __shfl_xor(dp, 16);
      if (tx == 0) d[c] = dp;
    }
  }
  __syncthreads();
  if (t < K1_) {
    float sv = p2b[0];
    for (int j = 0; j < K1_; ++j) sv = fmaf(As2s[t*K1_ + j], d[j], sv);
    s[t] = sv;
  }
  __syncthreads();
  if (t < K1_) {
    float si = s[t];
    int rank = 0;
    for (int j = 0; j < K1_; ++j) {
      float sj = s[j];
      rank += (sj > si) || (sj == si && j < t);
    }
    rankA[t] = rank;
    gA[t] = tanhf(si);
  }
  __syncthreads();
  // ---------------- rank-directed output + mean ----------------
  float4 zp = make_float4(0.f, 0.f, 0.f, 0.f);
#pragma unroll
  for (int i = 0; i < 8; ++i) {
    int c = ty*8 + i;
    if (c < K1_) {
      int r = rankA[c];
      if (r < K2_) {
        float gv = gA[c];
        float4 v = make_float4(aacc[i][0]*gv, aacc[i][1]*gv, aacc[i][2]*gv, aacc[i][3]*gv);
        *(float4*)(out + ((size_t)g*K2_ + r)*NOUT + 4*tx) = v;
        zp.x += v.x; zp.y += v.y; zp.z += v.z; zp.w += v.w;
      }
    }
  }
  __syncthreads();          // xs (aliased by zpart) fully dead
  zpart[ty*32 + tx] = zp;
  __syncthreads();
  if (t < 32) {
    float4 z = make_float4(0.f, 0.f, 0.f, 0.f);
#pragma unroll
    for (int k = 0; k < 8; ++k) {
      float4 v = zpart[k*32 + t];
      z.x += v.x; z.y += v.y; z.z += v.z; z.w += v.w;
    }
    const float inv = 1.0f / (float)K2_;
    z.x *= inv; z.y *= inv; z.z *= inv; z.w *= inv;
    *(float4*)(out + (size_t)G_*K2_*NOUT + (size_t)g*NOUT + 4*t) = z;
  }
}

extern "C" void kernel_launch(void* const* d_in, const int* in_sizes, int n_in,
                              void* d_out, int out_size, void* d_ws, size_t ws_size,
                              hipStream_t stream) {
  const float* h    = (const float*)d_in[0];
  const int*   ei   = (const int*)  d_in[1];
  const float* ew   = (const float*)d_in[2];
  const float* gc1w = (const float*)d_in[3];
  const float* gc1b = (const float*)d_in[4];
  const float* bn1g = (const float*)d_in[5];
  const float* bn1b = (const float*)d_in[6];
  const float* bn1m = (const float*)d_in[7];
  const float* bn1v = (const float*)d_in[8];
  const float* pr1a = (const float*)d_in[9];
  const float* p1w  = (const float*)d_in[10];
  const float* p1b  = (const float*)d_in[11];
  const float* gc2w = (const float*)d_in[12];
  const float* gc2b = (const float*)d_in[13];
  const float* bn2g = (const float*)d_in[14];
  const float* bn2b = (const float*)d_in[15];
  const float* bn2m = (const float*)d_in[16];
  const float* bn2v = (const float*)d_in[17];
  const float* pr2a = (const float*)d_in[18];
  const float* p2w  = (const float*)d_in[19];
  const float* p2b  = (const float*)d_in[20];

  float* w = (float*)d_ws;
  // float offsets
  float*          A1      = w;                               // 4096
  float*          As1     = w + 4096;                        // 4096
  float*          dots2   = w + 8192;                        // 131072
  int*            nidx    = (int*)(w + 139264);              // 65536
  int*            rowsrc  = (int*)(w + 204800);              // 53248
  float*          rowgate = w + 258048;                      // 53248
  unsigned short* W1thi   = (unsigned short*)(w + 311296);   // 16384 fl
  unsigned short* W1tlo   = (unsigned short*)(w + 327680);   // 16384 fl
  unsigned short* W2thi   = (unsigned short*)(w + 344064);   // 16384 fl
  unsigned short* W2tmid  = (unsigned short*)(w + 360448);   // 16384 fl
  unsigned short* W2tlo   = (unsigned short*)(w + 376832);   // 16384 fl
  float*          xa2     = w + 393216;                      // 8388608
  unsigned short* xahi    = (unsigned short*)(w + 8781824);  // 4194304 fl
  unsigned short* xalo    = (unsigned short*)(w + 12976128); // 4194304 fl
  float*          y1      = w + 17170432;                    // 16777216 fl -> 33947648

  prep_all<<<129, 256, 0, stream>>>(ei, ew, gc1w, gc2w, A1, As1,
                                    W1thi, W1tlo, W2thi, W2tmid, W2tlo);
  preagg_b<<<1024, 256, 0, stream>>>(h, A1, xa2);
  xa_cvt<<<1024, 256, 0, stream>>>(xa2, xahi, xalo);
  gemm1m<<<dim3(1024, 2), 256, 0, stream>>>(xahi, xalo, W1thi, W1tlo, gc1b,
                                            bn1g, bn1b, bn1m, bn1v, pr1a, p1w,
                                            y1, dots2);
  pool1s<<<G_, 256, 0, stream>>>(dots2, As1, p1b, rowsrc, rowgate, nidx);
  mega2f<<<G_, 256, 0, stream>>>(y1, rowsrc, rowgate, W2thi, W2tmid, W2tlo,
                                 ei, ew, nidx, gc2b, bn2g, bn2b, bn2m, bn2v,
                                 pr2a, p2w, p2b, (float*)d_out);
}